// Round 25
// baseline (238.556 us; speedup 1.0000x reference)
//
#include <hip/hip_runtime.h>
#include <hip/hip_fp16.h>
#include <math.h>

#define N_NODES 50000
#define N_EDGES 800000
#define D 128
#define BN_EPS 1e-5f
#define N_TILES 3125   // 50000 / 16
#define CAP 48         // bucket capacity per row (max deg ~40)
#define SPMM_BLOCKS 2048
#define SCOLS 32       // columns per XCD-pinned slice in spmm
#define BINS 512       // fine row bins (== spmm rank count)
#define RPB 98         // rows per fine bin (512*98 = 50176 >= N_NODES)
#define EPB 3125       // edges per pass-A sort block
#define SORTB 256      // pass-A sort blocks
#define BCAP 2048      // fine segment capacity (mean 1562, +12 sigma)
#define GEMMB 782      // gemm blocks (4 tiles per 256-thr block)
// two-level radix
#define NCOARSE 8
#define CAPA 320       // stage slots per coarse bin (remainder<64 + batch 256 = 319 max)
#define CHUNKA 64      // flush chunk (512 B)
#define CCAP 106496    // coarse segment capacity (mean ~100k)
#define NFINE 64       // fine bins per coarse
#define CAPB 64        // stage slots per fine bin
#define CHUNKB 32      // flush chunk (256 B)
#define PASSB_BLOCKS 256   // 32 blocks per coarse segment

typedef __attribute__((ext_vector_type(8))) _Float16 half8;
typedef __attribute__((ext_vector_type(4))) float floatx4;

// ---------------- octonion Hamilton tables ----------------
__device__ __constant__ int OCT_C[8][8] = {
    {0,1,2,3,4,5,6,7},
    {1,0,3,2,5,4,7,6},
    {2,3,0,1,6,7,4,5},
    {3,2,1,0,7,6,5,4},
    {4,5,6,7,0,1,2,3},
    {5,4,7,6,1,0,3,2},
    {6,7,4,5,2,3,0,1},
    {7,6,5,4,3,2,1,0}};
__device__ __constant__ float OCT_S[8][8] = {
    { 1,-1,-1,-1,-1,-1,-1,-1},
    { 1, 1,-1, 1,-1, 1, 1,-1},
    { 1, 1, 1,-1,-1,-1, 1, 1},
    { 1,-1, 1, 1,-1, 1,-1, 1},
    { 1, 1, 1, 1, 1,-1,-1,-1},
    { 1,-1, 1,-1, 1, 1, 1,-1},
    { 1,-1,-1, 1, 1,-1, 1, 1},
    { 1, 1,-1,-1, 1, 1,-1, 1}};

// ---------------- setup: Ht + zero stats/bintail/coarsetail ----------------
__global__ __launch_bounds__(256) void setup_kernel(const float* __restrict__ W,
                                                    __half* __restrict__ Ht,
                                                    float* __restrict__ stats,
                                                    int* __restrict__ bintail,
                                                    int* __restrict__ coarsetail) {
    const int i = blockIdx.x * 256 + threadIdx.x;   // 64 blocks -> 16384
    if (i < D * D) {
        int ccol = i >> 7, k = i & 127;
        int ii = k >> 4, kw = k & 15, j = ccol >> 4, m = ccol & 15;
        Ht[i] = __float2half(OCT_S[j][ii] * W[kw * D + OCT_C[j][ii] * 16 + m]);
    }
    if (i < 2 * D) stats[i] = 0.0f;
    if (i < BINS * 16) bintail[i] = 0;
    if (i < NCOARSE * 16) coarsetail[i] = 0;
}

// ---------------- k2: role-split — pass-A coarse radix scatter | MFMA gemm ----------------
// Sort blocks [0,256): stage edges into 8 coarse bins in LDS, flush 64-edge
// (512 B) chunks coalesced — no random global writes. Gemm blocks [256,1038).
__global__ __launch_bounds__(256) void sortgemm_kernel(const int* __restrict__ arow,
                                                       const int* __restrict__ acol,
                                                       const float* __restrict__ aval,
                                                       int* __restrict__ coarsetail,
                                                       uint2* __restrict__ coarse,
                                                       const float* __restrict__ in,
                                                       const __half* __restrict__ Ht,
                                                       __half* __restrict__ support) {
    __shared__ uint2 stageA[NCOARSE * CAPA];   // 20480 B
    __shared__ int fillA[NCOARSE], nfA[NCOARSE], fbA[NCOARSE];
    const int b = blockIdx.x;
    const int tid = threadIdx.x;
    if (b < SORTB) {
        if (tid < NCOARSE) fillA[tid] = 0;
        __syncthreads();
        const int e0 = b * EPB, e1 = e0 + EPB;
        for (int base = e0; base < e1; base += 256) {
            const int i = base + tid;
            if (i < e1) {
                int r = arow[i];
                int bin = r / RPB;                  // 0..511
                int g = bin >> 6;                   // 0..7
                unsigned hv = (unsigned)__half_as_ushort(__float2half(aval[i]));
                unsigned pk = ((unsigned)acol[i] & 0xFFFFu) | (hv << 16);
                int pos = atomicAdd(&fillA[g], 1);  // <= 319 deterministically
                stageA[g * CAPA + pos] = make_uint2(pk, (unsigned)r);
            }
            __syncthreads();
            if (tid < NCOARSE) {
                int n = fillA[tid];
                int nf = n & ~(CHUNKA - 1);
                nfA[tid] = nf;
                fbA[tid] = nf ? atomicAdd(&coarsetail[tid * 16], nf) : 0;
            }
            __syncthreads();
            for (int g = 0; g < NCOARSE; ++g) {
                int nf = nfA[g];
                if (!nf) continue;
                int wl = CCAP - fbA[g]; if (wl < 0) wl = 0;
                int nw = nf < wl ? nf : wl;
                uint2* dst = coarse + (size_t)g * CCAP + fbA[g];
                for (int j = tid; j < nw; j += 256) dst[j] = stageA[g * CAPA + j];
            }
            __syncthreads();
            for (int g = 0; g < NCOARSE; ++g) {
                int n = fillA[g], nf = nfA[g];
                if (tid < n - nf) stageA[g * CAPA + tid] = stageA[g * CAPA + nf + tid];
            }
            __syncthreads();
            if (tid < NCOARSE) fillA[tid] -= nfA[tid];
            __syncthreads();
        }
        // final drain (remainders < 64 per bin)
        if (tid < NCOARSE) {
            int n = fillA[tid];
            nfA[tid] = n;
            fbA[tid] = n ? atomicAdd(&coarsetail[tid * 16], n) : 0;
        }
        __syncthreads();
        for (int g = 0; g < NCOARSE; ++g) {
            int n = nfA[g];
            if (!n) continue;
            int wl = CCAP - fbA[g]; if (wl < 0) wl = 0;
            int nw = n < wl ? n : wl;
            uint2* dst = coarse + (size_t)g * CCAP + fbA[g];
            for (int j = tid; j < nw; j += 256) dst[j] = stageA[g * CAPA + j];
        }
        return;
    }
    // ---- gemm: tile = (b-SORTB)*4 + wave ----
    const int wv = tid >> 6;
    const int tile = (b - SORTB) * 4 + wv;
    if (tile >= N_TILES) return;
    const int lane = tid & 63;
    const int s = lane & 15;
    const int t = lane >> 4;

    half8 bb[8][4];
#pragma unroll
    for (int kk = 0; kk < 4; ++kk)
#pragma unroll
        for (int n = 0; n < 8; ++n)
            bb[n][kk] = *reinterpret_cast<const half8*>(Ht + (size_t)(16 * n + s) * D + kk * 32 + 8 * t);

    const float* ap = in + (size_t)(tile * 16 + s) * D;
    half8 a[4];
#pragma unroll
    for (int kk = 0; kk < 4; ++kk) {
        float4 f0 = *reinterpret_cast<const float4*>(ap + kk * 32 + 8 * t);
        float4 f1 = *reinterpret_cast<const float4*>(ap + kk * 32 + 8 * t + 4);
        a[kk][0] = (_Float16)f0.x; a[kk][1] = (_Float16)f0.y;
        a[kk][2] = (_Float16)f0.z; a[kk][3] = (_Float16)f0.w;
        a[kk][4] = (_Float16)f1.x; a[kk][5] = (_Float16)f1.y;
        a[kk][6] = (_Float16)f1.z; a[kk][7] = (_Float16)f1.w;
    }

    floatx4 acc[8];
#pragma unroll
    for (int n = 0; n < 8; ++n) acc[n] = (floatx4){0.f, 0.f, 0.f, 0.f};
#pragma unroll
    for (int kk = 0; kk < 4; ++kk)
#pragma unroll
        for (int n = 0; n < 8; ++n)
            acc[n] = __builtin_amdgcn_mfma_f32_16x16x32_f16(a[kk], bb[n][kk], acc[n], 0, 0, 0);

    __half* sp = support + (size_t)(tile * 16 + 4 * t) * D + s;
#pragma unroll
    for (int r = 0; r < 4; ++r)
#pragma unroll
        for (int n = 0; n < 8; ++n)
            sp[(size_t)r * D + 16 * n] = __float2half(acc[n][r]);
}

// ---------------- pass B: coarse segment -> 64 fine bins, LDS-staged chunk flushes ----------------
__global__ __launch_bounds__(256) void passb_kernel(const int* __restrict__ coarsetail,
                                                    const uint2* __restrict__ coarse,
                                                    int* __restrict__ bintail,
                                                    uint2* __restrict__ binned) {
    __shared__ uint2 stageB[NFINE * CAPB];     // 32768 B
    __shared__ int fillB[NFINE], nfB[NFINE], fbB[NFINE], stB[NFINE];
    const int b = blockIdx.x;
    const int tid = threadIdx.x;
    const int g = b & 7;               // coarse group
    const int sr = b >> 3;             // 0..31 within group
    const int finebase = g * NFINE;    // global fine bin base
    int ng = coarsetail[g * 16];
    if (ng > CCAP) ng = CCAP;
    const int per = (ng + 31) / 32;
    const int s0 = sr * per;
    int s1 = s0 + per; if (s1 > ng) s1 = ng;
    const uint2* src = coarse + (size_t)g * CCAP;

    if (tid < NFINE) fillB[tid] = 0;
    __syncthreads();

    for (int base = s0; base < s1; base += 256) {
        const int i = base + tid;
        if (i < s1) {
            uint2 e = src[i];
            int bin = (int)e.y / RPB;          // global fine bin
            int lb = bin & 63;
            int pos = atomicAdd(&fillB[lb], 1);
            if (pos < CAPB) {
                stageB[lb * CAPB + pos] = e;
            } else {
                // statistically-never overflow: direct single write
                int idx = atomicAdd(&bintail[bin * 16], 1);
                if (idx < BCAP) binned[(size_t)bin * BCAP + idx] = e;
            }
        }
        __syncthreads();
        if (tid < NFINE) {
            int n = fillB[tid]; if (n > CAPB) n = CAPB;
            stB[tid] = n;
            int nf = n & ~(CHUNKB - 1);
            nfB[tid] = nf;
            fbB[tid] = nf ? atomicAdd(&bintail[(finebase + tid) * 16], nf) : 0;
        }
        __syncthreads();
        for (int fb = 0; fb < NFINE; ++fb) {
            int nf = nfB[fb];
            if (!nf) continue;
            int wl = BCAP - fbB[fb]; if (wl < 0) wl = 0;
            int nw = nf < wl ? nf : wl;
            uint2* dst = binned + (size_t)(finebase + fb) * BCAP + fbB[fb];
            for (int j = tid; j < nw; j += 256) dst[j] = stageB[fb * CAPB + j];
        }
        __syncthreads();
        for (int fb = 0; fb < NFINE; ++fb) {
            int n = stB[fb], nf = nfB[fb];
            if (tid < n - nf) stageB[fb * CAPB + tid] = stageB[fb * CAPB + nf + tid];
        }
        __syncthreads();
        if (tid < NFINE) fillB[tid] = stB[tid] - nfB[tid];
        __syncthreads();
    }
    // final drain (remainders < 32 per bin)
    if (tid < NFINE) {
        int n = fillB[tid];
        nfB[tid] = n;
        fbB[tid] = n ? atomicAdd(&bintail[(finebase + tid) * 16], n) : 0;
    }
    __syncthreads();
    for (int fb = 0; fb < NFINE; ++fb) {
        int n = nfB[fb];
        if (!n) continue;
        int wl = BCAP - fbB[fb]; if (wl < 0) wl = 0;
        int nw = n < wl ? n : wl;
        uint2* dst = binned + (size_t)(finebase + fb) * BCAP + fbB[fb];
        for (int j = tid; j < nw; j += 256) dst[j] = stageB[fb * CAPB + j];
    }
}

// ---------------- k3: fused bucket-build (LDS) + spmm (R23 known-good) ----------------
__global__ __launch_bounds__(256) void spmm_kernel(const int* __restrict__ bintail,
                                                   const uint2* __restrict__ binned,
                                                   const __half* __restrict__ support,
                                                   __half* __restrict__ outh,
                                                   float* __restrict__ colsum,
                                                   float* __restrict__ colsq) {
    __shared__ unsigned lbucket[RPB * CAP];   // 18816 B
    __shared__ int lcnt[RPB];
    __shared__ float lsum[SCOLS], lsq[SCOLS];

    const int tid = threadIdx.x;
    const int b = blockIdx.x;
    const int slice = (b & 7) >> 1;                    // 0..3 (XCD-pair pinned)
    const int rank = ((b >> 3) << 1) | (b & 1);        // 0..511 == bin
    const int rbase = rank * RPB;

    // ---- phase A: zero + build LDS bucket for this bin ----
    if (tid < RPB) lcnt[tid] = 0;
    if (tid < SCOLS) { lsum[tid] = 0.f; lsq[tid] = 0.f; }
    for (int k = tid; k < RPB * CAP; k += 256) lbucket[k] = 0u;
    __syncthreads();
    int nb = bintail[rank * 16];
    nb = nb < BCAP ? nb : BCAP;
    const unsigned long long* seg = reinterpret_cast<const unsigned long long*>(
        binned + (size_t)rank * BCAP);
    for (int i = tid; i < nb; i += 256) {
        unsigned long long e = __builtin_nontemporal_load(seg + i);
        int rl = (int)(e >> 32) - rbase;
        int slot = atomicAdd(&lcnt[rl], 1);
        if (slot < CAP) lbucket[rl * CAP + slot] = (unsigned)e;
    }
    __syncthreads();

    // ---- phase B: spmm over this bin's rows, this block's column slice ----
    const int lane = tid & 63;
    const int wv = tid >> 6;
    const int h = lane >> 4;          // edge group 0..3
    const int cl = lane & 15;         // column lane
    const int colbase = slice * SCOLS + cl * 2;
    const unsigned cb2 = (unsigned)(colbase * 2);
    const char* sbase = reinterpret_cast<const char*>(support);

    float s0 = 0.f, s1 = 0.f, q0 = 0.f, q1 = 0.f;

    for (int rl = wv * 2; rl < RPB; rl += 8) {
        const int row = rbase + rl;
        const int rowb = row + 1;
        int na = lcnt[rl]; na = na < CAP ? na : CAP;
        int nb2 = (rl + 1 < RPB) ? lcnt[rl + 1] : 0; nb2 = nb2 < CAP ? nb2 : CAP;
        const int nmax = na > nb2 ? na : nb2;
        __half2 acca = __half2half2(__ushort_as_half((unsigned short)0));
        __half2 accb = acca;

        // stage 1: slots 0..31 (8 j-groups, 16 gathers in flight)
        {
            unsigned ua[8], ub[8];
            __half2 ga[8], gb[8];
#pragma unroll
            for (int j = 0; j < 8; ++j) {
                ua[j] = lbucket[rl * CAP + j * 4 + h];
                ub[j] = lbucket[(rl + 1 < RPB ? rl + 1 : rl) * CAP + j * 4 + h];
            }
            if (rl + 1 >= RPB) {
#pragma unroll
                for (int j = 0; j < 8; ++j) ub[j] = 0u;
            }
#pragma unroll
            for (int j = 0; j < 8; ++j) {
                ga[j] = *reinterpret_cast<const __half2*>(sbase + (((ua[j] & 0xFFFFu) << 8) + cb2));
                gb[j] = *reinterpret_cast<const __half2*>(sbase + (((ub[j] & 0xFFFFu) << 8) + cb2));
            }
#pragma unroll
            for (int j = 0; j < 8; ++j) {
                unsigned va2 = __builtin_amdgcn_perm(ua[j], ua[j], 0x07060706u);
                unsigned vb2 = __builtin_amdgcn_perm(ub[j], ub[j], 0x07060706u);
                acca = __hfma2(*reinterpret_cast<__half2*>(&va2), ga[j], acca);
                accb = __hfma2(*reinterpret_cast<__half2*>(&vb2), gb[j], accb);
            }
        }
        // stage 2: slots 32..47 (only when a row exceeds 32 edges)
        if (nmax > 32) {
            unsigned ua[4], ub[4];
            __half2 ga[4], gb[4];
#pragma unroll
            for (int j = 0; j < 4; ++j) {
                ua[j] = lbucket[rl * CAP + 32 + j * 4 + h];
                ub[j] = lbucket[(rl + 1 < RPB ? rl + 1 : rl) * CAP + 32 + j * 4 + h];
            }
            if (rl + 1 >= RPB) {
#pragma unroll
                for (int j = 0; j < 4; ++j) ub[j] = 0u;
            }
#pragma unroll
            for (int j = 0; j < 4; ++j) {
                ga[j] = *reinterpret_cast<const __half2*>(sbase + (((ua[j] & 0xFFFFu) << 8) + cb2));
                gb[j] = *reinterpret_cast<const __half2*>(sbase + (((ub[j] & 0xFFFFu) << 8) + cb2));
            }
#pragma unroll
            for (int j = 0; j < 4; ++j) {
                unsigned va2 = __builtin_amdgcn_perm(ua[j], ua[j], 0x07060706u);
                unsigned vb2 = __builtin_amdgcn_perm(ub[j], ub[j], 0x07060706u);
                acca = __hfma2(*reinterpret_cast<__half2*>(&va2), ga[j], acca);
                accb = __hfma2(*reinterpret_cast<__half2*>(&vb2), gb[j], accb);
            }
        }

        // combine the 4 edge groups
#pragma unroll
        for (int off = 16; off <= 32; off <<= 1) {
            int ia = __shfl_xor(*reinterpret_cast<int*>(&acca), off);
            int ib = __shfl_xor(*reinterpret_cast<int*>(&accb), off);
            acca = __hadd2(acca, *reinterpret_cast<__half2*>(&ia));
            accb = __hadd2(accb, *reinterpret_cast<__half2*>(&ib));
        }
        if (h == 0) {
            if (row < N_NODES) {
                float2 fa = __half22float2(acca);
                __builtin_nontemporal_store(*reinterpret_cast<unsigned*>(&acca),
                    reinterpret_cast<unsigned*>(outh + (size_t)row * D + colbase));
                s0 += fa.x; s1 += fa.y; q0 += fa.x * fa.x; q1 += fa.y * fa.y;
            }
            if (rowb < N_NODES && rl + 1 < RPB) {
                float2 fb = __half22float2(accb);
                __builtin_nontemporal_store(*reinterpret_cast<unsigned*>(&accb),
                    reinterpret_cast<unsigned*>(outh + (size_t)rowb * D + colbase));
                s0 += fb.x; s1 += fb.y; q0 += fb.x * fb.x; q1 += fb.y * fb.y;
            }
        }
    }

    if (h == 0) {
        atomicAdd(&lsum[cl * 2 + 0], s0); atomicAdd(&lsum[cl * 2 + 1], s1);
        atomicAdd(&lsq[cl * 2 + 0], q0);  atomicAdd(&lsq[cl * 2 + 1], q1);
    }
    __syncthreads();
    if (tid < SCOLS) {
        atomicAdd(&colsum[slice * SCOLS + tid], lsum[tid]);
        atomicAdd(&colsq[slice * SCOLS + tid], lsq[tid]);
    }
}

// ---------------- BN + tanh: read fp16 outh, nt-write fp32 out ----------------
__global__ __launch_bounds__(256) void bn_tanh_kernel(const __half* __restrict__ outh,
                                                      float* __restrict__ out,
                                                      const float* __restrict__ colsum,
                                                      const float* __restrict__ colsq,
                                                      const float* __restrict__ gamma,
                                                      const float* __restrict__ beta) {
    __shared__ float scale[D], shift[D];
    const int tid = threadIdx.x;
    if (tid < D) {
        float mean = colsum[tid] * (1.0f / N_NODES);
        float var  = colsq[tid] * (1.0f / N_NODES) - mean * mean;
        float sc   = rsqrtf(var + BN_EPS) * gamma[tid];
        scale[tid] = sc;
        shift[tid] = beta[tid] - mean * sc;
    }
    __syncthreads();
    const int nq = N_NODES * D / 8;   // units of 8 halves
    floatx4* outv = reinterpret_cast<floatx4*>(out);
    for (int i = blockIdx.x * 256 + tid; i < nq; i += gridDim.x * 256) {
        uint4 v = reinterpret_cast<const uint4*>(outh)[i];
        const int c = (i & 15) * 8;
        float r[8];
        float2 f;
        f = __half22float2(*reinterpret_cast<__half2*>(&v.x)); r[0] = f.x; r[1] = f.y;
        f = __half22float2(*reinterpret_cast<__half2*>(&v.y)); r[2] = f.x; r[3] = f.y;
        f = __half22float2(*reinterpret_cast<__half2*>(&v.z)); r[4] = f.x; r[5] = f.y;
        f = __half22float2(*reinterpret_cast<__half2*>(&v.w)); r[6] = f.x; r[7] = f.y;
#pragma unroll
        for (int k = 0; k < 8; ++k) {
            float x = r[k] * scale[c + k] + shift[c + k];
            float e = __expf(2.0f * x);
            r[k] = 1.0f - 2.0f / (1.0f + e);
        }
        floatx4 o0 = {r[0], r[1], r[2], r[3]};
        floatx4 o1 = {r[4], r[5], r[6], r[7]};
        __builtin_nontemporal_store(o0, outv + i * 2 + 0);
        __builtin_nontemporal_store(o1, outv + i * 2 + 1);
    }
}

// ---------------- launch ----------------
extern "C" void kernel_launch(void* const* d_in, const int* in_sizes, int n_in,
                              void* d_out, int out_size, void* d_ws, size_t ws_size,
                              hipStream_t stream) {
    const float* input  = (const float*)d_in[0];
    const int*   arow   = (const int*)d_in[1];
    const int*   acol   = (const int*)d_in[2];
    const float* aval   = (const float*)d_in[3];
    const float* weight = (const float*)d_in[4];
    const float* gamma  = (const float*)d_in[5];
    const float* beta   = (const float*)d_in[6];
    float* out = (float*)d_out;

    __half*   support   = (__half*)d_ws;                              // 12.8 MB
    __half*   outh      = (__half*)(support + (size_t)N_NODES * D);   // 12.8 MB
    uint2*    coarse    = (uint2*)outh;                               // 6.8 MB, consumed before spmm writes outh
    uint2*    binned    = (uint2*)(outh + (size_t)N_NODES * D);       // 8.4 MB
    float*    colsum    = (float*)(binned + (size_t)BINS * BCAP);     // 128 (+128 colsq)
    float*    colsq     = colsum + D;
    int*      bintail   = (int*)(colsum + 2 * D);                     // 32 KB (64B-strided)
    int*      coarsetail= bintail + BINS * 16;                        // 512 B
    __half*   Ht        = (__half*)(coarsetail + NCOARSE * 16);       // 32 KB

    setup_kernel<<<64, 256, 0, stream>>>(weight, Ht, colsum, bintail, coarsetail);
    sortgemm_kernel<<<SORTB + GEMMB, 256, 0, stream>>>(arow, acol, aval, coarsetail, coarse,
                                                       input, Ht, support);
    passb_kernel<<<PASSB_BLOCKS, 256, 0, stream>>>(coarsetail, coarse, bintail, binned);
    spmm_kernel<<<SPMM_BLOCKS, 256, 0, stream>>>(bintail, binned, support, outh,
                                                 colsum, colsq);
    bn_tanh_kernel<<<2048, 256, 0, stream>>>(outh, out, colsum, colsq, gamma, beta);
}

// Round 26
// 85.904 us; speedup vs baseline: 2.7770x; 2.7770x over previous
//
#include <hip/hip_runtime.h>
#include <hip/hip_fp16.h>
#include <math.h>

#define N_NODES 50000
#define N_EDGES 800000
#define D 128
#define BN_EPS 1e-5f
#define N_TILES 3125   // 50000 / 16
#define CAP 48         // bucket capacity per row (max deg ~40)
#define SPMM_BLOCKS 2048
#define SCOLS 32       // columns per XCD-pinned slice in spmm
#define BINS 512       // row bins (== spmm rank count)
#define RPB 98         // rows per bin (512*98 = 50176 >= N_NODES)
#define EPB 3125       // edges per sort block
#define SORTB 256      // sort blocks
#define BCAP 2048      // segment capacity per bin (mean 1562, +12 sigma)
#define GEMMB 782      // gemm blocks (4 tiles per 256-thr block)

typedef __attribute__((ext_vector_type(8))) _Float16 half8;
typedef __attribute__((ext_vector_type(4))) float floatx4;

// ---------------- octonion Hamilton tables ----------------
__device__ __constant__ int OCT_C[8][8] = {
    {0,1,2,3,4,5,6,7},
    {1,0,3,2,5,4,7,6},
    {2,3,0,1,6,7,4,5},
    {3,2,1,0,7,6,5,4},
    {4,5,6,7,0,1,2,3},
    {5,4,7,6,1,0,3,2},
    {6,7,4,5,2,3,0,1},
    {7,6,5,4,3,2,1,0}};
__device__ __constant__ float OCT_S[8][8] = {
    { 1,-1,-1,-1,-1,-1,-1,-1},
    { 1, 1,-1, 1,-1, 1, 1,-1},
    { 1, 1, 1,-1,-1,-1, 1, 1},
    { 1,-1, 1, 1,-1, 1,-1, 1},
    { 1, 1, 1, 1, 1,-1,-1,-1},
    { 1,-1, 1,-1, 1, 1, 1,-1},
    { 1,-1,-1, 1, 1,-1, 1, 1},
    { 1, 1,-1,-1, 1, 1,-1, 1}};

// ---------------- setup: Ht + zero stats/bintail ----------------
__global__ __launch_bounds__(256) void setup_kernel(const float* __restrict__ W,
                                                    __half* __restrict__ Ht,
                                                    float* __restrict__ stats,
                                                    int* __restrict__ bintail) {
    const int i = blockIdx.x * 256 + threadIdx.x;   // 64 blocks -> 16384
    if (i < D * D) {
        int ccol = i >> 7, k = i & 127;
        int ii = k >> 4, kw = k & 15, j = ccol >> 4, m = ccol & 15;
        Ht[i] = __float2half(OCT_S[j][ii] * W[kw * D + OCT_C[j][ii] * 16 + m]);
    }
    if (i < 2 * D) stats[i] = 0.0f;
    if (i < BINS * 16) bintail[i] = 0;
}

// ---------------- k2: role-split — counting-sort blocks | MFMA gemm blocks ----------------
// Sort blocks [0,256): LDS counting sort of EPB edges by bin, then stream the
// bin-ordered stage to global — runs of the same bin hit consecutive addresses,
// cutting random write line-ops ~6x. Gemm blocks [256,1038): 4 tiles each.
__global__ __launch_bounds__(256) void sortgemm_kernel(const int* __restrict__ arow,
                                                       const int* __restrict__ acol,
                                                       const float* __restrict__ aval,
                                                       int* __restrict__ bintail,
                                                       uint2* __restrict__ binned,
                                                       const float* __restrict__ in,
                                                       const __half* __restrict__ Ht,
                                                       __half* __restrict__ support) {
    __shared__ uint2 stage[EPB];                       // 25000 B, bin-ordered edges
    __shared__ int hist[BINS], pref[BINS], lbase[BINS], cursor[BINS];
    __shared__ int wtot[4];
    const int b = blockIdx.x;
    const int tid = threadIdx.x;
    if (b < SORTB) {
        const int lane = tid & 63, wid = tid >> 6;
        hist[tid] = 0; hist[tid + 256] = 0;
        __syncthreads();
        const int e0 = b * EPB, e1 = e0 + EPB;
        // ---- pass 1: histogram ----
        for (int i = e0 + tid; i < e1; i += 256)
            atomicAdd(&hist[arow[i] / RPB], 1);
        __syncthreads();
        // ---- block exclusive prefix sum over 512 bins (2 per thread) ----
        int v0 = hist[2 * tid], v1 = hist[2 * tid + 1];
        int s = v0 + v1;
        int incl = s;
#pragma unroll
        for (int off = 1; off < 64; off <<= 1) {
            int t = __shfl_up(incl, off, 64);
            if (lane >= off) incl += t;
        }
        if (lane == 63) wtot[wid] = incl;
        __syncthreads();
        if (tid == 0) {
            int acc = 0;
#pragma unroll
            for (int w = 0; w < 4; ++w) { int t = wtot[w]; wtot[w] = acc; acc += t; }
        }
        __syncthreads();
        int excl = wtot[wid] + incl - s;
        pref[2 * tid] = excl;
        pref[2 * tid + 1] = excl + v0;
        // ---- reserve global segment space (1 atomic per (block,bin)) ----
        cursor[2 * tid] = excl;
        cursor[2 * tid + 1] = excl + v0;
        lbase[2 * tid]     = v0 ? atomicAdd(&bintail[(2 * tid) * 16], v0) : 0;
        lbase[2 * tid + 1] = v1 ? atomicAdd(&bintail[(2 * tid + 1) * 16], v1) : 0;
        __syncthreads();
        // ---- pass 2: stage edges bin-ordered in LDS ----
        for (int i = e0 + tid; i < e1; i += 256) {
            int r = arow[i];
            int bin = r / RPB;
            unsigned hv = (unsigned)__half_as_ushort(__float2half(aval[i]));
            unsigned pk = ((unsigned)acol[i] & 0xFFFFu) | (hv << 16);
            int pos = atomicAdd(&cursor[bin], 1);
            stage[pos] = make_uint2(pk, (unsigned)r);
        }
        __syncthreads();
        // ---- stream out: same-bin runs -> consecutive global addresses ----
        for (int j = tid; j < EPB; j += 256) {
            uint2 e = stage[j];
            int bin = (int)e.y / RPB;
            int gidx = lbase[bin] + (j - pref[bin]);
            if (gidx < BCAP) binned[(size_t)bin * BCAP + gidx] = e;
        }
        return;
    }
    // ---- gemm: tile = (b-SORTB)*4 + wave ----
    const int wv = tid >> 6;
    const int tile = (b - SORTB) * 4 + wv;
    if (tile >= N_TILES) return;
    const int lane = tid & 63;
    const int s = lane & 15;
    const int t = lane >> 4;

    half8 bb[8][4];
#pragma unroll
    for (int kk = 0; kk < 4; ++kk)
#pragma unroll
        for (int n = 0; n < 8; ++n)
            bb[n][kk] = *reinterpret_cast<const half8*>(Ht + (size_t)(16 * n + s) * D + kk * 32 + 8 * t);

    const float* ap = in + (size_t)(tile * 16 + s) * D;
    half8 a[4];
#pragma unroll
    for (int kk = 0; kk < 4; ++kk) {
        float4 f0 = *reinterpret_cast<const float4*>(ap + kk * 32 + 8 * t);
        float4 f1 = *reinterpret_cast<const float4*>(ap + kk * 32 + 8 * t + 4);
        a[kk][0] = (_Float16)f0.x; a[kk][1] = (_Float16)f0.y;
        a[kk][2] = (_Float16)f0.z; a[kk][3] = (_Float16)f0.w;
        a[kk][4] = (_Float16)f1.x; a[kk][5] = (_Float16)f1.y;
        a[kk][6] = (_Float16)f1.z; a[kk][7] = (_Float16)f1.w;
    }

    floatx4 acc[8];
#pragma unroll
    for (int n = 0; n < 8; ++n) acc[n] = (floatx4){0.f, 0.f, 0.f, 0.f};
#pragma unroll
    for (int kk = 0; kk < 4; ++kk)
#pragma unroll
        for (int n = 0; n < 8; ++n)
            acc[n] = __builtin_amdgcn_mfma_f32_16x16x32_f16(a[kk], bb[n][kk], acc[n], 0, 0, 0);

    __half* sp = support + (size_t)(tile * 16 + 4 * t) * D + s;
#pragma unroll
    for (int r = 0; r < 4; ++r)
#pragma unroll
        for (int n = 0; n < 8; ++n)
            sp[(size_t)r * D + 16 * n] = __float2half(acc[n][r]);
}

// ---------------- k3: fused bucket-build (LDS) + spmm (R23 known-good) ----------------
__global__ __launch_bounds__(256) void spmm_kernel(const int* __restrict__ bintail,
                                                   const uint2* __restrict__ binned,
                                                   const __half* __restrict__ support,
                                                   __half* __restrict__ outh,
                                                   float* __restrict__ colsum,
                                                   float* __restrict__ colsq) {
    __shared__ unsigned lbucket[RPB * CAP];   // 18816 B
    __shared__ int lcnt[RPB];
    __shared__ float lsum[SCOLS], lsq[SCOLS];

    const int tid = threadIdx.x;
    const int b = blockIdx.x;
    const int slice = (b & 7) >> 1;                    // 0..3 (XCD-pair pinned)
    const int rank = ((b >> 3) << 1) | (b & 1);        // 0..511 == bin
    const int rbase = rank * RPB;

    // ---- phase A: zero + build LDS bucket for this bin ----
    if (tid < RPB) lcnt[tid] = 0;
    if (tid < SCOLS) { lsum[tid] = 0.f; lsq[tid] = 0.f; }
    for (int k = tid; k < RPB * CAP; k += 256) lbucket[k] = 0u;
    __syncthreads();
    int nb = bintail[rank * 16];
    nb = nb < BCAP ? nb : BCAP;
    const unsigned long long* seg = reinterpret_cast<const unsigned long long*>(
        binned + (size_t)rank * BCAP);
    for (int i = tid; i < nb; i += 256) {
        unsigned long long e = __builtin_nontemporal_load(seg + i);
        int rl = (int)(e >> 32) - rbase;
        int slot = atomicAdd(&lcnt[rl], 1);
        if (slot < CAP) lbucket[rl * CAP + slot] = (unsigned)e;
    }
    __syncthreads();

    // ---- phase B: spmm over this bin's rows, this block's column slice ----
    const int lane = tid & 63;
    const int wv = tid >> 6;
    const int h = lane >> 4;          // edge group 0..3
    const int cl = lane & 15;         // column lane
    const int colbase = slice * SCOLS + cl * 2;
    const unsigned cb2 = (unsigned)(colbase * 2);
    const char* sbase = reinterpret_cast<const char*>(support);

    float s0 = 0.f, s1 = 0.f, q0 = 0.f, q1 = 0.f;

    for (int rl = wv * 2; rl < RPB; rl += 8) {
        const int row = rbase + rl;
        const int rowb = row + 1;
        int na = lcnt[rl]; na = na < CAP ? na : CAP;
        int nb2 = (rl + 1 < RPB) ? lcnt[rl + 1] : 0; nb2 = nb2 < CAP ? nb2 : CAP;
        const int nmax = na > nb2 ? na : nb2;
        __half2 acca = __half2half2(__ushort_as_half((unsigned short)0));
        __half2 accb = acca;

        // stage 1: slots 0..31 (8 j-groups, 16 gathers in flight)
        {
            unsigned ua[8], ub[8];
            __half2 ga[8], gb[8];
#pragma unroll
            for (int j = 0; j < 8; ++j) {
                ua[j] = lbucket[rl * CAP + j * 4 + h];
                ub[j] = lbucket[(rl + 1 < RPB ? rl + 1 : rl) * CAP + j * 4 + h];
            }
            if (rl + 1 >= RPB) {
#pragma unroll
                for (int j = 0; j < 8; ++j) ub[j] = 0u;
            }
#pragma unroll
            for (int j = 0; j < 8; ++j) {
                ga[j] = *reinterpret_cast<const __half2*>(sbase + (((ua[j] & 0xFFFFu) << 8) + cb2));
                gb[j] = *reinterpret_cast<const __half2*>(sbase + (((ub[j] & 0xFFFFu) << 8) + cb2));
            }
#pragma unroll
            for (int j = 0; j < 8; ++j) {
                unsigned va2 = __builtin_amdgcn_perm(ua[j], ua[j], 0x07060706u);
                unsigned vb2 = __builtin_amdgcn_perm(ub[j], ub[j], 0x07060706u);
                acca = __hfma2(*reinterpret_cast<__half2*>(&va2), ga[j], acca);
                accb = __hfma2(*reinterpret_cast<__half2*>(&vb2), gb[j], accb);
            }
        }
        // stage 2: slots 32..47 (only when a row exceeds 32 edges)
        if (nmax > 32) {
            unsigned ua[4], ub[4];
            __half2 ga[4], gb[4];
#pragma unroll
            for (int j = 0; j < 4; ++j) {
                ua[j] = lbucket[rl * CAP + 32 + j * 4 + h];
                ub[j] = lbucket[(rl + 1 < RPB ? rl + 1 : rl) * CAP + 32 + j * 4 + h];
            }
            if (rl + 1 >= RPB) {
#pragma unroll
                for (int j = 0; j < 4; ++j) ub[j] = 0u;
            }
#pragma unroll
            for (int j = 0; j < 4; ++j) {
                ga[j] = *reinterpret_cast<const __half2*>(sbase + (((ua[j] & 0xFFFFu) << 8) + cb2));
                gb[j] = *reinterpret_cast<const __half2*>(sbase + (((ub[j] & 0xFFFFu) << 8) + cb2));
            }
#pragma unroll
            for (int j = 0; j < 4; ++j) {
                unsigned va2 = __builtin_amdgcn_perm(ua[j], ua[j], 0x07060706u);
                unsigned vb2 = __builtin_amdgcn_perm(ub[j], ub[j], 0x07060706u);
                acca = __hfma2(*reinterpret_cast<__half2*>(&va2), ga[j], acca);
                accb = __hfma2(*reinterpret_cast<__half2*>(&vb2), gb[j], accb);
            }
        }

        // combine the 4 edge groups
#pragma unroll
        for (int off = 16; off <= 32; off <<= 1) {
            int ia = __shfl_xor(*reinterpret_cast<int*>(&acca), off);
            int ib = __shfl_xor(*reinterpret_cast<int*>(&accb), off);
            acca = __hadd2(acca, *reinterpret_cast<__half2*>(&ia));
            accb = __hadd2(accb, *reinterpret_cast<__half2*>(&ib));
        }
        if (h == 0) {
            if (row < N_NODES) {
                float2 fa = __half22float2(acca);
                __builtin_nontemporal_store(*reinterpret_cast<unsigned*>(&acca),
                    reinterpret_cast<unsigned*>(outh + (size_t)row * D + colbase));
                s0 += fa.x; s1 += fa.y; q0 += fa.x * fa.x; q1 += fa.y * fa.y;
            }
            if (rowb < N_NODES && rl + 1 < RPB) {
                float2 fb = __half22float2(accb);
                __builtin_nontemporal_store(*reinterpret_cast<unsigned*>(&accb),
                    reinterpret_cast<unsigned*>(outh + (size_t)rowb * D + colbase));
                s0 += fb.x; s1 += fb.y; q0 += fb.x * fb.x; q1 += fb.y * fb.y;
            }
        }
    }

    if (h == 0) {
        atomicAdd(&lsum[cl * 2 + 0], s0); atomicAdd(&lsum[cl * 2 + 1], s1);
        atomicAdd(&lsq[cl * 2 + 0], q0);  atomicAdd(&lsq[cl * 2 + 1], q1);
    }
    __syncthreads();
    if (tid < SCOLS) {
        atomicAdd(&colsum[slice * SCOLS + tid], lsum[tid]);
        atomicAdd(&colsq[slice * SCOLS + tid], lsq[tid]);
    }
}

// ---------------- BN + tanh: read fp16 outh, nt-write fp32 out ----------------
__global__ __launch_bounds__(256) void bn_tanh_kernel(const __half* __restrict__ outh,
                                                      float* __restrict__ out,
                                                      const float* __restrict__ colsum,
                                                      const float* __restrict__ colsq,
                                                      const float* __restrict__ gamma,
                                                      const float* __restrict__ beta) {
    __shared__ float scale[D], shift[D];
    const int tid = threadIdx.x;
    if (tid < D) {
        float mean = colsum[tid] * (1.0f / N_NODES);
        float var  = colsq[tid] * (1.0f / N_NODES) - mean * mean;
        float sc   = rsqrtf(var + BN_EPS) * gamma[tid];
        scale[tid] = sc;
        shift[tid] = beta[tid] - mean * sc;
    }
    __syncthreads();
    const int nq = N_NODES * D / 8;   // units of 8 halves
    floatx4* outv = reinterpret_cast<floatx4*>(out);
    for (int i = blockIdx.x * 256 + tid; i < nq; i += gridDim.x * 256) {
        uint4 v = reinterpret_cast<const uint4*>(outh)[i];
        const int c = (i & 15) * 8;
        float r[8];
        float2 f;
        f = __half22float2(*reinterpret_cast<__half2*>(&v.x)); r[0] = f.x; r[1] = f.y;
        f = __half22float2(*reinterpret_cast<__half2*>(&v.y)); r[2] = f.x; r[3] = f.y;
        f = __half22float2(*reinterpret_cast<__half2*>(&v.z)); r[4] = f.x; r[5] = f.y;
        f = __half22float2(*reinterpret_cast<__half2*>(&v.w)); r[6] = f.x; r[7] = f.y;
#pragma unroll
        for (int k = 0; k < 8; ++k) {
            float x = r[k] * scale[c + k] + shift[c + k];
            float e = __expf(2.0f * x);
            r[k] = 1.0f - 2.0f / (1.0f + e);
        }
        floatx4 o0 = {r[0], r[1], r[2], r[3]};
        floatx4 o1 = {r[4], r[5], r[6], r[7]};
        __builtin_nontemporal_store(o0, outv + i * 2 + 0);
        __builtin_nontemporal_store(o1, outv + i * 2 + 1);
    }
}

// ---------------- launch ----------------
extern "C" void kernel_launch(void* const* d_in, const int* in_sizes, int n_in,
                              void* d_out, int out_size, void* d_ws, size_t ws_size,
                              hipStream_t stream) {
    const float* input  = (const float*)d_in[0];
    const int*   arow   = (const int*)d_in[1];
    const int*   acol   = (const int*)d_in[2];
    const float* aval   = (const float*)d_in[3];
    const float* weight = (const float*)d_in[4];
    const float* gamma  = (const float*)d_in[5];
    const float* beta   = (const float*)d_in[6];
    float* out = (float*)d_out;

    __half*   support = (__half*)d_ws;                              // 12.8 MB
    __half*   outh    = (__half*)(support + (size_t)N_NODES * D);   // 12.8 MB
    uint2*    binned  = (uint2*)(outh + (size_t)N_NODES * D);       // 8.4 MB
    float*    colsum  = (float*)(binned + (size_t)BINS * BCAP);     // 128 (+128 colsq)
    float*    colsq   = colsum + D;
    int*      bintail = (int*)(colsum + 2 * D);                     // 32 KB (64B-strided)
    __half*   Ht      = (__half*)(bintail + BINS * 16);             // 32 KB

    setup_kernel<<<64, 256, 0, stream>>>(weight, Ht, colsum, bintail);
    sortgemm_kernel<<<SORTB + GEMMB, 256, 0, stream>>>(arow, acol, aval, bintail, binned,
                                                       input, Ht, support);
    spmm_kernel<<<SPMM_BLOCKS, 256, 0, stream>>>(bintail, binned, support, outh,
                                                 colsum, colsq);
    bn_tanh_kernel<<<2048, 256, 0, stream>>>(outh, out, colsum, colsq, gamma, beta);
}